// Round 11
// baseline (336.952 us; speedup 1.0000x reference)
//
#include <hip/hip_runtime.h>
#include <hip/hip_bf16.h>
#include <math.h>

#define N_NODES 50000
#define F_IN 256
#define H1 128
#define C_OUT 40
#define L1W 384   // 3*H1
#define L2W 120   // 3*C_OUT
#define L2WP 128  // padded
#define NBUK 196  // ceil(50000/256) dst buckets of 256 nodes
#define NBLK1 256 // phase-1 blocks

typedef __attribute__((ext_vector_type(8))) short short8;
typedef __attribute__((ext_vector_type(4))) float f32x4;
typedef __attribute__((ext_vector_type(2))) float f32x2;

typedef __attribute__((address_space(1))) const unsigned int gu32;
typedef __attribute__((address_space(3))) unsigned int lu32;

__device__ __forceinline__ void g2l16(const void* g, void* l) {
    __builtin_amdgcn_global_load_lds((gu32*)g, (lu32*)l, 16, 0, 0);
}

__device__ inline unsigned short f2bf(float f) {
    union { float f; unsigned int u; } x;
    x.f = f;
    unsigned int u = x.u;
    return (unsigned short)((u + 0x7FFF + ((u >> 16) & 1)) >> 16);
}
__device__ inline float bf2f(unsigned short u) {
    union { unsigned int u; float f; } x;
    x.u = (unsigned int)u << 16;
    return x.f;
}
__device__ inline unsigned int pack_fp8x4(float a, float b, float c, float d) {
    int v = 0;
    v = __builtin_amdgcn_cvt_pk_fp8_f32(a, b, v, false);  // bytes 0,1
    v = __builtin_amdgcn_cvt_pk_fp8_f32(c, d, v, true);   // bytes 2,3
    return (unsigned int)v;
}
__device__ inline unsigned short pack_fp8x2(float a, float b) {
    return (unsigned short)(__builtin_amdgcn_cvt_pk_fp8_f32(a, b, 0, false) & 0xFFFF);
}
__device__ inline unsigned char pack_fp8x1(float a) {
    return (unsigned char)(__builtin_amdgcn_cvt_pk_fp8_f32(a, a, 0, false) & 0xFF);
}
// decode 4B edge record {w:bf16:16 | src:16}
#define EDGE_S(r) ((int)((r) & 0xFFFFu))
#define EDGE_W(r) bf2f((unsigned short)((r) >> 16))

// ---------------- inline edge-index dtype detection (per-wave, no launch) ----

__device__ __forceinline__ bool detect_i32(const int* __restrict__ ei) {
    int lane = threadIdx.x & 63;
    int v = ei[2 * lane + 1] | ei[2 * (lane + 64) + 1] |
            ei[2 * (lane + 128) + 1] | ei[2 * (lane + 192) + 1];
    return __ballot(v != 0) != 0ULL;
}

// ---------------- fused: per-node hist + bucket hist + weight pack ----------

#define N1PACK ((F_IN / 32) * L1W * 32)
#define N2PACK ((L1W / 32) * L2WP * 32)
#define PACKB ((N1PACK + N2PACK + 255) / 256)

__global__ __launch_bounds__(256) void fhist_k(const int* __restrict__ ei,
                                               const float* __restrict__ w10,
                                               const float* __restrict__ w11,
                                               const float* __restrict__ w12,
                                               const float* __restrict__ w20,
                                               const float* __restrict__ w21,
                                               const float* __restrict__ w22,
                                               int* __restrict__ cnt,
                                               int* __restrict__ cnt2,
                                               unsigned short* __restrict__ Bp1,
                                               unsigned short* __restrict__ Bp2, int E) {
    __shared__ int lcnt[NBUK];
    int t = threadIdx.x, blk = blockIdx.x;
    if (blk < NBLK1) {
        bool i32 = detect_i32(ei);
        for (int j = t; j < NBUK; j += 256) lcnt[j] = 0;
        __syncthreads();
        int chunk = (E + NBLK1 - 1) / NBLK1;
        int beg = blk * chunk, end = min(beg + chunk, E);
        const long long* e64 = (const long long*)ei;
        for (int e = beg + t; e < end; e += 256) {
            int d = i32 ? ei[E + e] : (int)e64[E + e];
            atomicAdd(&cnt[d], 1);
            atomicAdd(&lcnt[d >> 8], 1);
        }
        __syncthreads();
        for (int j = t; j < NBUK; j += 256) cnt2[j * NBLK1 + blk] = lcnt[j];  // bucket-major
    } else {
        int idx = (blk - NBLK1) * 256 + t;
        if (idx < N1PACK) {
            int kt = idx / (L1W * 32);
            int tt = idx % (L1W * 32);
            int s = tt >> 9;
            int u = tt & 511;
            int kq = u >> 7, m = (u >> 3) & 15, kk = u & 7;
            int col = s * 16 + m;
            int k = kt * 32 + kq * 8 + kk;
            int p = col >> 7, c = col & 127;
            const float* w = (p == 0) ? w10 : (p == 1) ? w11 : w12;
            Bp1[idx] = f2bf(w[k * H1 + c]);
        } else if (idx < N1PACK + N2PACK) {
            int j = idx - N1PACK;
            int kt = j / (L2WP * 32);
            int tt = j % (L2WP * 32);
            int s = tt >> 9;
            int u = tt & 511;
            int kq = u >> 7, m = (u >> 3) & 15, kk = u & 7;
            int col = s * 16 + m;
            int k = kt * 32 + kq * 8 + kk;
            unsigned short v = 0;
            if (col < L2W) {
                int p = col / 40, c = col % 40;
                const float* w = (p == 0) ? w20 : (p == 1) ? w21 : w22;
                v = f2bf(w[k * C_OUT + c]);
            }
            Bp2[j] = v;
        }
    }
}

// ---------------- fused 3-level exclusive scans (node chain + bucket chain) --

__global__ __launch_bounds__(256) void fscan1_k(const int* __restrict__ cntA,
                                                int* __restrict__ bsumA, int nA,
                                                const int* __restrict__ cntB,
                                                int* __restrict__ bsumB, int nB, int nbA) {
    int b = blockIdx.x;
    const int* cnt;
    int* bsum;
    int n, bb;
    if (b < nbA) { cnt = cntA; bsum = bsumA; n = nA; bb = b; }
    else         { cnt = cntB; bsum = bsumB; n = nB; bb = b - nbA; }
    int t = threadIdx.x;
    int i = bb * 256 + t;
    int v = (i < n) ? cnt[i] : 0;
    for (int off = 32; off; off >>= 1) v += __shfl_down(v, off, 64);
    __shared__ int ws[4];
    if ((t & 63) == 0) ws[t >> 6] = v;
    __syncthreads();
    if (t == 0) bsum[bb] = ws[0] + ws[1] + ws[2] + ws[3];
}

__global__ __launch_bounds__(256) void fscan2_k(int* __restrict__ bsumA,
                                                int* __restrict__ btotA, int nbA,
                                                int* __restrict__ bsumB,
                                                int* __restrict__ btotB, int nbB) {
    int* bsum;
    int* btot;
    int nb;
    if (blockIdx.x == 0) { bsum = bsumA; btot = btotA; nb = nbA; }
    else                 { bsum = bsumB; btot = btotB; nb = nbB; }
    __shared__ int s[256];
    int t = threadIdx.x;
    int v = (t < nb) ? bsum[t] : 0;
    s[t] = v;
    __syncthreads();
    for (int off = 1; off < 256; off <<= 1) {
        int u = (t >= off) ? s[t - off] : 0;
        __syncthreads();
        s[t] += u;
        __syncthreads();
    }
    if (t < nb) bsum[t] = s[t] - v;  // exclusive
    if (t == nb - 1) *btot = s[t];
}

__global__ __launch_bounds__(256) void fscan3_k(const int* __restrict__ cntA,
                                                const int* __restrict__ bsumA,
                                                int* __restrict__ rpA,
                                                float* __restrict__ dinv, int nA,
                                                const int* __restrict__ cntB,
                                                const int* __restrict__ bsumB,
                                                int* __restrict__ rpB, int nB, int nbA) {
    int b = blockIdx.x;
    const int* cnt;
    const int* bsum;
    int* rowptr;
    float* dv;
    int n, bb;
    if (b < nbA) { cnt = cntA; bsum = bsumA; rowptr = rpA; dv = dinv; n = nA; bb = b; }
    else         { cnt = cntB; bsum = bsumB; rowptr = rpB; dv = nullptr; n = nB; bb = b - nbA; }
    __shared__ int s[256];
    int t = threadIdx.x;
    int i = bb * 256 + t;
    int v = (i < n) ? cnt[i] : 0;
    s[t] = v;
    __syncthreads();
    for (int off = 1; off < 256; off <<= 1) {
        int u = (t >= off) ? s[t - off] : 0;
        __syncthreads();
        s[t] += u;
        __syncthreads();
    }
    if (i < n) {
        rowptr[i] = s[t] - v + bsum[bb];
        if (dv) dv[i] = rsqrtf((float)v + 1.0f);
    }
}

// ---------------- binned stage (phase 1 of scatter) -------------------------

__global__ __launch_bounds__(256) void stage_k(const int* __restrict__ ei,
                                               const int* __restrict__ off2,
                                               unsigned int* __restrict__ stage, int E) {
    __shared__ int lcur[NBUK];
    bool i32 = detect_i32(ei);
    int t = threadIdx.x, blk = blockIdx.x;
    for (int j = t; j < NBUK; j += 256) lcur[j] = off2[j * NBLK1 + blk];
    __syncthreads();
    int chunk = (E + NBLK1 - 1) / NBLK1;
    int beg = blk * chunk, end = min(beg + chunk, E);
    const long long* e64 = (const long long*)ei;
    for (int e = beg + t; e < end; e += 256) {
        int s, d;
        if (i32) { s = ei[e]; d = ei[E + e]; }
        else { s = (int)e64[e]; d = (int)e64[E + e]; }
        int b = d >> 8;
        int pos = atomicAdd(&lcur[b], 1);
        stage[pos] = ((unsigned int)(d & 255) << 16) | (unsigned int)s;
    }
}

// ---------------- FUSED: scatter2 (blocks 0..NBUK) + layer-1 GEMM -----------
// GEMM: counted-vmcnt pipeline, raw barriers, (256,3): LDS 50176*3 <= 160KB.

__global__ __launch_bounds__(256, 3) void scmg1_k(const unsigned int* __restrict__ stage,
                                                  const int* __restrict__ off2,
                                                  const int* __restrict__ rowptr,
                                                  const float* __restrict__ dinv,
                                                  unsigned int* __restrict__ csr, int E,
                                                  const float* __restrict__ A,
                                                  const unsigned short* __restrict__ Bp,
                                                  const float* __restrict__ b1,
                                                  unsigned short* __restrict__ Hb,
                                                  unsigned char* __restrict__ Y8, int N) {
    __shared__ unsigned short Bls[2][L1W * 32];  // 2 slots x 24 KB (GEMM)
    __shared__ int lfill[256];                   // scatter
    int tid = threadIdx.x;
    if (blockIdx.x < NBUK) {
        // ---- scatter2 body ----
        int b = blockIdx.x, t = tid;
        int node0 = b << 8;
        int node = node0 + t;
        lfill[t] = (node < N) ? rowptr[node] : 0;
        __syncthreads();
        int segBeg = off2[b * NBLK1];
        int segEnd = (b == NBUK - 1) ? E : off2[(b + 1) * NBLK1];
        for (int e = segBeg + t; e < segEnd; e += 256) {
            unsigned int rec = stage[e];
            int dl = rec >> 16;
            int s = rec & 0xFFFF;
            int d = node0 + dl;
            float w = dinv[s] * dinv[d];
            int pos = atomicAdd(&lfill[dl], 1);
            csr[pos] = ((unsigned int)f2bf(w) << 16) | (unsigned int)s;
        }
        return;
    }
    // ---- mgemm1 body ----
    int w = tid >> 6, lane = tid & 63;
    int m = lane & 15, kq = lane >> 4;
    int row0 = (blockIdx.x - NBUK) * 64 + w * 16;
    int arow = row0 + m;
    if (arow >= N) arow = N - 1;  // clamped duplicate; stores guarded
    const float* Ap = A + (size_t)arow * F_IN + kq * 8;
    const char* srcb = (const char*)Bp + (size_t)(w * 6) * 1024 + (size_t)lane * 16;

    float4 at0[8], at1[8];
#pragma unroll
    for (int kt = 0; kt < 8; kt++) {
        at0[kt] = *(const float4*)(Ap + kt * 32);
        at1[kt] = *(const float4*)(Ap + kt * 32 + 4);
    }
#pragma unroll
    for (int j = 0; j < 6; j++) g2l16(srcb + j * 1024, &Bls[0][(w * 6 + j) * 512]);
#pragma unroll
    for (int j = 0; j < 6; j++) g2l16(srcb + 24576 + j * 1024, &Bls[1][(w * 6 + j) * 512]);
    short8 areg[8];
#pragma unroll
    for (int kt = 0; kt < 8; kt++) {
        float4 u = at0[kt], v = at1[kt];
        short8 a;
        a[0] = (short)f2bf(u.x); a[1] = (short)f2bf(u.y);
        a[2] = (short)f2bf(u.z); a[3] = (short)f2bf(u.w);
        a[4] = (short)f2bf(v.x); a[5] = (short)f2bf(v.y);
        a[6] = (short)f2bf(v.z); a[7] = (short)f2bf(v.w);
        areg[kt] = a;
    }

    f32x4 acc[24];
#pragma unroll
    for (int s = 0; s < 24; s++) acc[s] = (f32x4){0.f, 0.f, 0.f, 0.f};

#pragma unroll
    for (int kt = 0; kt < 8; kt++) {
        if (kt < 7) { asm volatile("s_waitcnt vmcnt(6)" ::: "memory"); }
        else        { asm volatile("s_waitcnt vmcnt(0)" ::: "memory"); }
        __builtin_amdgcn_s_barrier();
        __builtin_amdgcn_sched_barrier(0);
        const unsigned short* Bbuf = Bls[kt & 1];
        __builtin_amdgcn_s_setprio(1);
#pragma unroll
        for (int c = 0; c < 4; c++) {
            short8 bf[6];
#pragma unroll
            for (int j = 0; j < 6; j++)
                bf[j] = *(const short8*)(&Bbuf[(c * 6 + j) * 512 + lane * 8]);
#pragma unroll
            for (int j = 0; j < 6; j++)
                acc[c * 6 + j] = __builtin_amdgcn_mfma_f32_16x16x32_bf16(
                    areg[kt], bf[j], acc[c * 6 + j], 0, 0, 0);
        }
        __builtin_amdgcn_s_setprio(0);
        asm volatile("s_waitcnt lgkmcnt(0)" ::: "memory");  // reads retired
        __builtin_amdgcn_s_barrier();                       // slot kt reusable
        if (kt < 6) {
#pragma unroll
            for (int j = 0; j < 6; j++)
                g2l16(srcb + (size_t)(kt + 2) * 24576 + j * 1024,
                      &Bls[kt & 1][(w * 6 + j) * 512]);
        }
    }

    int crow = row0 + kq * 4;
#pragma unroll
    for (int s = 0; s < 8; s++) {
        int col = s * 16 + m;
        float bias = b1[col];
#pragma unroll
        for (int r2 = 0; r2 < 4; r2++) {
            int row = crow + r2;
            if (row < N) Hb[(size_t)row * L1W + col] = f2bf(fmaxf(acc[s][r2] + bias, 0.f));
        }
    }
#pragma unroll
    for (int r2 = 0; r2 < 4; r2++) {
        int row = crow + r2;
        if (row < N) {
            uint4 u;
            u.x = pack_fp8x4(acc[8][r2], acc[9][r2], acc[10][r2], acc[11][r2]);
            u.y = pack_fp8x4(acc[12][r2], acc[13][r2], acc[14][r2], acc[15][r2]);
            u.z = pack_fp8x4(acc[16][r2], acc[17][r2], acc[18][r2], acc[19][r2]);
            u.w = pack_fp8x4(acc[20][r2], acc[21][r2], acc[22][r2], acc[23][r2]);
            *(uint4*)(Y8 + (size_t)row * 256 + m * 16) = u;
        }
    }
}

// ---------------- layer-2 GEMM: counted-vmcnt structure ---------------------

__global__ __launch_bounds__(256, 3) void mgemm2_k(const unsigned short* __restrict__ A,
                                                   const unsigned short* __restrict__ Bp,
                                                   unsigned short* __restrict__ Ub,
                                                   unsigned char* __restrict__ U8, int N) {
    __shared__ unsigned short Bls[2][L2WP * 32];  // 2 slots x 8 KB
    int tid = threadIdx.x;
    int w = tid >> 6, lane = tid & 63;
    int m = lane & 15, kq = lane >> 4;
    int row0 = blockIdx.x * 64 + w * 16;
    int arow = row0 + m;
    if (arow >= N) arow = N - 1;
    const unsigned short* Ap = A + (size_t)arow * L1W + kq * 8;
    const char* srcb = (const char*)Bp + (size_t)(w * 2) * 1024 + (size_t)lane * 16;

    short8 areg[12];
#pragma unroll
    for (int kt = 0; kt < 12; kt++) areg[kt] = *(const short8*)(Ap + kt * 32);
#pragma unroll
    for (int j = 0; j < 2; j++) g2l16(srcb + j * 1024, &Bls[0][(w * 2 + j) * 512]);
#pragma unroll
    for (int j = 0; j < 2; j++) g2l16(srcb + 8192 + j * 1024, &Bls[1][(w * 2 + j) * 512]);

    f32x4 acc[8];
#pragma unroll
    for (int s = 0; s < 8; s++) acc[s] = (f32x4){0.f, 0.f, 0.f, 0.f};

#pragma unroll
    for (int kt = 0; kt < 12; kt++) {
        if (kt < 11) { asm volatile("s_waitcnt vmcnt(2)" ::: "memory"); }
        else         { asm volatile("s_waitcnt vmcnt(0)" ::: "memory"); }
        __builtin_amdgcn_s_barrier();
        __builtin_amdgcn_sched_barrier(0);
        const unsigned short* Bbuf = Bls[kt & 1];
        __builtin_amdgcn_s_setprio(1);
        short8 bf[8];
#pragma unroll
        for (int j = 0; j < 8; j++)
            bf[j] = *(const short8*)(&Bbuf[j * 512 + lane * 8]);
#pragma unroll
        for (int j = 0; j < 8; j++)
            acc[j] = __builtin_amdgcn_mfma_f32_16x16x32_bf16(areg[kt], bf[j], acc[j], 0, 0, 0);
        __builtin_amdgcn_s_setprio(0);
        asm volatile("s_waitcnt lgkmcnt(0)" ::: "memory");
        __builtin_amdgcn_s_barrier();
        if (kt < 10) {
#pragma unroll
            for (int j = 0; j < 2; j++)
                g2l16(srcb + (size_t)(kt + 2) * 8192 + j * 1024,
                      &Bls[kt & 1][(w * 2 + j) * 512]);
        }
    }

    int crow = row0 + kq * 4;
#pragma unroll
    for (int s = 0; s < 3; s++) {
        int col = s * 16 + m;
#pragma unroll
        for (int r2 = 0; r2 < 4; r2++) {
            int row = crow + r2;
            if (row < N) Ub[(size_t)row * L2WP + col] = f2bf(acc[s][r2]);
        }
    }
#pragma unroll
    for (int r2 = 0; r2 < 4; r2++) {
        int row = crow + r2;
        if (row < N) {
            uint2 u;
            u.x = pack_fp8x4(acc[0][r2], acc[1][r2], acc[2][r2], acc[3][r2]);
            u.y = pack_fp8x4(acc[4][r2], acc[5][r2], acc[6][r2], acc[7][r2]);
            *(uint2*)(U8 + (size_t)row * 128 + m * 8) = u;
        }
    }
}

// ---------------- width-256 fp8 prop: DUAL-ROW per wave ---------------------
// Each wave owns rows i0,i0+1: two independent gather chains interleaved in
// one instruction stream (wave-uniform branches only; no per-element masks
// in the main loop). Weights extracted before csr reload; masked tail per row.

__device__ __forceinline__ void ep256(unsigned short* __restrict__ Hb,
                                      unsigned char* __restrict__ T8,
                                      const float* __restrict__ b1, int i, int lane,
                                      float a0, float a1, float a2, float a3) {
    int m = lane >> 2, jj = lane & 3;
    if (jj < 2) {  // z1: logical cols L_j = (4*jj+j)*16 + m
        float av[4] = {a0, a1, a2, a3};
#pragma unroll
        for (int j = 0; j < 4; j++) {
            int L = (4 * jj + j) * 16 + m;
            Hb[(size_t)i * L1W + 128 + L] = f2bf(fmaxf(av[j] + b1[128 + L], 0.f));
        }
    } else {       // t2 -> T8 phys = m*8 + 4*(jj-2)
        unsigned int o = pack_fp8x4(a0, a1, a2, a3);
        *(unsigned int*)(T8 + (size_t)i * 128 + m * 8 + 4 * (jj - 2)) = o;
    }
}

__global__ __launch_bounds__(256) void prop256f_k(const unsigned char* __restrict__ Y8,
                                                  unsigned short* __restrict__ Hb,
                                                  unsigned char* __restrict__ T8,
                                                  const int* __restrict__ rowptr,
                                                  const unsigned int* __restrict__ csr,
                                                  const float* __restrict__ dinv,
                                                  const float* __restrict__ b1, int n) {
    int wave = threadIdx.x >> 6, lane = threadIdx.x & 63;
    int i0 = blockIdx.x * 8 + wave * 2;
    if (i0 >= n) return;
    int i1 = i0 + 1;
    bool hasB = i1 < n;
    int begA = rowptr[i0], endA = rowptr[i0 + 1];
    int begB = 0, endB = 0;
    if (hasB) { begB = rowptr[i1]; endB = rowptr[i1 + 1]; }
    const unsigned int* sbase = (const unsigned int*)Y8 + lane;  // row stride 64 uints

    float aA0, aA1, aA2, aA3;
    float aB0 = 0.f, aB1 = 0.f, aB2 = 0.f, aB3 = 0.f;
    {
        float di = dinv[i0];
        float w = di * di;
        unsigned int sv = sbase[(size_t)i0 * 64];
        f32x2 lo = __builtin_amdgcn_cvt_pk_f32_fp8(sv, false);
        f32x2 hi = __builtin_amdgcn_cvt_pk_f32_fp8(sv, true);
        aA0 = w * lo.x; aA1 = w * lo.y; aA2 = w * hi.x; aA3 = w * hi.y;
    }
    if (hasB) {
        float di = dinv[i1];
        float w = di * di;
        unsigned int sv = sbase[(size_t)i1 * 64];
        f32x2 lo = __builtin_amdgcn_cvt_pk_f32_fp8(sv, false);
        f32x2 hi = __builtin_amdgcn_cvt_pk_f32_fp8(sv, true);
        aB0 = w * lo.x; aB1 = w * lo.y; aB2 = w * hi.x; aB3 = w * hi.y;
    }

    int nfA = (endA - begA) >> 3, nfB = (endB - begB) >> 3;
    unsigned int rrA[8], rrB[8];
    if (nfA > 0) {
#pragma unroll
        for (int e = 0; e < 8; e++) rrA[e] = csr[begA + e];
    }
    if (nfB > 0) {
#pragma unroll
        for (int e = 0; e < 8; e++) rrB[e] = csr[begB + e];
    }
    int nmax = nfA > nfB ? nfA : nfB;
    for (int it = 0; it < nmax; it++) {
        unsigned int vvA[8], vvB[8];
        float wA[8], wB[8];
        bool doA = it < nfA, doB = it < nfB;
        if (doA) {
#pragma unroll
            for (int e = 0; e < 8; e++) vvA[e] = sbase[(size_t)EDGE_S(rrA[e]) * 64];
        }
        if (doB) {
#pragma unroll
            for (int e = 0; e < 8; e++) vvB[e] = sbase[(size_t)EDGE_S(rrB[e]) * 64];
        }
        if (doA) {
#pragma unroll
            for (int e = 0; e < 8; e++) wA[e] = __uint_as_float(rrA[e] & 0xFFFF0000u);
        }
        if (doB) {
#pragma unroll
            for (int e = 0; e < 8; e++) wB[e] = __uint_as_float(rrB[e] & 0xFFFF0000u);
        }
        if (it + 1 < nfA) {
#pragma unroll
            for (int e = 0; e < 8; e++) rrA[e] = csr[begA + ((it + 1) << 3) + e];
        }
        if (it + 1 < nfB) {
#pragma unroll
            for (int e = 0; e < 8; e++) rrB[e] = csr[begB + ((it + 1) << 3) + e];
        }
        if (doA) {
#pragma unroll
            for (int e = 0; e < 8; e++) {
                f32x2 lo = __builtin_amdgcn_cvt_pk_f32_fp8(vvA[e], false);
                f32x2 hi = __builtin_amdgcn_cvt_pk_f32_fp8(vvA[e], true);
                aA0 = fmaf(wA[e], lo.x, aA0);
                aA1 = fmaf(wA[e], lo.y, aA1);
                aA2 = fmaf(wA[e], hi.x, aA2);
                aA3 = fmaf(wA[e], hi.y, aA3);
            }
        }
        if (doB) {
#pragma unroll
            for (int e = 0; e < 8; e++) {
                f32x2 lo = __builtin_amdgcn_cvt_pk_f32_fp8(vvB[e], false);
                f32x2 hi = __builtin_amdgcn_cvt_pk_f32_fp8(vvB[e], true);
                aB0 = fmaf(wB[e], lo.x, aB0);
                aB1 = fmaf(wB[e], lo.y, aB1);
                aB2 = fmaf(wB[e], hi.x, aB2);
                aB3 = fmaf(wB[e], hi.y, aB3);
            }
        }
    }
    // masked tails (one per row)
    {
        int k = begA + (nfA << 3);
        if (k < endA) {
            unsigned int rrt[8], vv[8];
#pragma unroll
            for (int e = 0; e < 8; e++) {
                int idx = k + e;
                rrt[e] = csr[idx < endA ? idx : begA];
            }
#pragma unroll
            for (int e = 0; e < 8; e++) vv[e] = sbase[(size_t)EDGE_S(rrt[e]) * 64];
#pragma unroll
            for (int e = 0; e < 8; e++) {
                float we = (k + e < endA) ? __uint_as_float(rrt[e] & 0xFFFF0000u) : 0.f;
                f32x2 lo = __builtin_amdgcn_cvt_pk_f32_fp8(vv[e], false);
                f32x2 hi = __builtin_amdgcn_cvt_pk_f32_fp8(vv[e], true);
                aA0 = fmaf(we, lo.x, aA0);
                aA1 = fmaf(we, lo.y, aA1);
                aA2 = fmaf(we, hi.x, aA2);
                aA3 = fmaf(we, hi.y, aA3);
            }
        }
    }
    if (hasB) {
        int k = begB + (nfB << 3);
        if (k < endB) {
            unsigned int rrt[8], vv[8];
#pragma unroll
            for (int e = 0; e < 8; e++) {
                int idx = k + e;
                rrt[e] = csr[idx < endB ? idx : begB];
            }
#pragma unroll
            for (int e = 0; e < 8; e++) vv[e] = sbase[(size_t)EDGE_S(rrt[e]) * 64];
#pragma unroll
            for (int e = 0; e < 8; e++) {
                float we = (k + e < endB) ? __uint_as_float(rrt[e] & 0xFFFF0000u) : 0.f;
                f32x2 lo = __builtin_amdgcn_cvt_pk_f32_fp8(vv[e], false);
                f32x2 hi = __builtin_amdgcn_cvt_pk_f32_fp8(vv[e], true);
                aB0 = fmaf(we, lo.x, aB0);
                aB1 = fmaf(we, lo.y, aB1);
                aB2 = fmaf(we, hi.x, aB2);
                aB3 = fmaf(we, hi.y, aB3);
            }
        }
    }
    ep256(Hb, T8, b1, i0, lane, aA0, aA1, aA2, aA3);
    if (hasB) ep256(Hb, T8, b1, i1, lane, aB0, aB1, aB2, aB3);
}

// ---------------- width-128 fp8 prop: DUAL-ROW per wave ---------------------

__device__ __forceinline__ void ep128(unsigned short* __restrict__ Hb,
                                      const float* __restrict__ b1, int i, int lane,
                                      float a0, float a1) {
    int m = lane >> 2, u0 = (2 * lane) & 7;
    int L0 = u0 * 16 + m, L1 = (u0 + 1) * 16 + m;
    Hb[(size_t)i * L1W + 256 + L0] = f2bf(fmaxf(a0 + b1[256 + L0], 0.f));
    Hb[(size_t)i * L1W + 256 + L1] = f2bf(fmaxf(a1 + b1[256 + L1], 0.f));
}

__global__ __launch_bounds__(256) void prop128f_k(const unsigned char* __restrict__ T8,
                                                  unsigned short* __restrict__ Hb,
                                                  const int* __restrict__ rowptr,
                                                  const unsigned int* __restrict__ csr,
                                                  const float* __restrict__ dinv,
                                                  const float* __restrict__ b1, int n) {
    int wave = threadIdx.x >> 6, lane = threadIdx.x & 63;
    int i0 = blockIdx.x * 8 + wave * 2;
    if (i0 >= n) return;
    int i1 = i0 + 1;
    bool hasB = i1 < n;
    int begA = rowptr[i0], endA = rowptr[i0 + 1];
    int begB = 0, endB = 0;
    if (hasB) { begB = rowptr[i1]; endB = rowptr[i1 + 1]; }
    const unsigned short* sbase = (const unsigned short*)T8 + lane;  // row stride 64

    float aA0, aA1, aB0 = 0.f, aB1 = 0.f;
    {
        float di = dinv[i0];
        float w = di * di;
        unsigned int sv = sbase[(size_t)i0 * 64];
        f32x2 d = __builtin_amdgcn_cvt_pk_f32_fp8(sv, false);
        aA0 = w * d.x; aA1 = w * d.y;
    }
    if (hasB) {
        float di = dinv[i1];
        float w = di * di;
        unsigned int sv = sbase[(size_t)i1 * 64];
        f32x2 d = __builtin_amdgcn_cvt_pk_f32_fp8(sv, false);
        aB0 = w * d.x; aB1 = w * d.y;
    }

    int nfA = (endA - begA) >> 3, nfB = (endB - begB) >> 3;
    unsigned int rrA[8], rrB[8];
    if (nfA > 0) {
#pragma unroll
        for (int e = 0; e < 8; e++) rrA[e] = csr[begA + e];
    }
    if (nfB > 0) {
#pragma unroll
        for (int e = 0; e < 8; e++) rrB[e] = csr[begB + e];
    }
    int nmax = nfA > nfB ? nfA : nfB;
    for (int it = 0; it < nmax; it++) {
        unsigned int vvA[8], vvB[8];
        float wA[8], wB[8];
        bool doA = it < nfA, doB = it < nfB;
        if (doA) {
#pragma unroll
            for (int e = 0; e < 8; e++) vvA[e] = sbase[(size_t)EDGE_S(rrA[e]) * 64];
        }
        if (doB) {
#pragma unroll
            for (int e = 0; e < 8; e++) vvB[e] = sbase[(size_t)EDGE_S(rrB[e]) * 64];
        }
        if (doA) {
#pragma unroll
            for (int e = 0; e < 8; e++) wA[e] = __uint_as_float(rrA[e] & 0xFFFF0000u);
        }
        if (doB) {
#pragma unroll
            for (int e = 0; e < 8; e++) wB[e] = __uint_as_float(rrB[e] & 0xFFFF0000u);
        }
        if (it + 1 < nfA) {
#pragma unroll
            for (int e = 0; e < 8; e++) rrA[e] = csr[begA + ((it + 1) << 3) + e];
        }
        if (it + 1 < nfB) {
#pragma unroll
            for (int e = 0; e < 8; e++) rrB[e] = csr[begB + ((it + 1) << 3) + e];
        }
        if (doA) {
#pragma unroll
            for (int e = 0; e < 8; e++) {
                f32x2 d = __builtin_amdgcn_cvt_pk_f32_fp8(vvA[e], false);
                aA0 = fmaf(wA[e], d.x, aA0);
                aA1 = fmaf(wA[e], d.y, aA1);
            }
        }
        if (doB) {
#pragma unroll
            for (int e = 0; e < 8; e++) {
                f32x2 d = __builtin_amdgcn_cvt_pk_f32_fp8(vvB[e], false);
                aB0 = fmaf(wB[e], d.x, aB0);
                aB1 = fmaf(wB[e], d.y, aB1);
            }
        }
    }
    {
        int k = begA + (nfA << 3);
        if (k < endA) {
            unsigned int rrt[8], vv[8];
#pragma unroll
            for (int e = 0; e < 8; e++) {
                int idx = k + e;
                rrt[e] = csr[idx < endA ? idx : begA];
            }
#pragma unroll
            for (int e = 0; e < 8; e++) vv[e] = sbase[(size_t)EDGE_S(rrt[e]) * 64];
#pragma unroll
            for (int e = 0; e < 8; e++) {
                float we = (k + e < endA) ? __uint_as_float(rrt[e] & 0xFFFF0000u) : 0.f;
                f32x2 d = __builtin_amdgcn_cvt_pk_f32_fp8(vv[e], false);
                aA0 = fmaf(we, d.x, aA0);
                aA1 = fmaf(we, d.y, aA1);
            }
        }
    }
    if (hasB) {
        int k = begB + (nfB << 3);
        if (k < endB) {
            unsigned int rrt[8], vv[8];
#pragma unroll
            for (int e = 0; e < 8; e++) {
                int idx = k + e;
                rrt[e] = csr[idx < endB ? idx : begB];
            }
#pragma unroll
            for (int e = 0; e < 8; e++) vv[e] = sbase[(size_t)EDGE_S(rrt[e]) * 64];
#pragma unroll
            for (int e = 0; e < 8; e++) {
                float we = (k + e < endB) ? __uint_as_float(rrt[e] & 0xFFFF0000u) : 0.f;
                f32x2 d = __builtin_amdgcn_cvt_pk_f32_fp8(vv[e], false);
                aB0 = fmaf(we, d.x, aB0);
                aB1 = fmaf(we, d.y, aB1);
            }
        }
    }
    ep128(Hb, b1, i0, lane, aA0, aA1);
    if (hasB) ep128(Hb, b1, i1, lane, aB0, aB1);
}

// ---------------- layer-2 prop over U8: 2 edge-groups x 32 cols -------------
// batch-of-4 per group + csr ping-pong prefetch + masked final batch

__global__ __launch_bounds__(256) void propU8_k(const unsigned char* __restrict__ U8,
                                                unsigned short* __restrict__ T2a,
                                                unsigned char* __restrict__ T8b,
                                                const int* __restrict__ rowptr,
                                                const unsigned int* __restrict__ csr,
                                                const float* __restrict__ dinv, int n) {
    int wave = threadIdx.x >> 6, lane = threadIdx.x & 63;
    int i = blockIdx.x * 4 + wave;
    if (i >= n) return;
    int beg = rowptr[i], end = rowptr[i + 1];
    float di = dinv[i];
    int g = lane >> 5, c = lane & 31;
    const unsigned int* sbase = (const unsigned int*)U8 + c;  // row stride 32 uints
    float a0 = 0.f, a1 = 0.f, a2 = 0.f, a3 = 0.f;
    if (g == 0) {
        unsigned int sv = sbase[(size_t)i * 32];
        float w = di * di;
        f32x2 lo = __builtin_amdgcn_cvt_pk_f32_fp8(sv, false);
        f32x2 hi = __builtin_amdgcn_cvt_pk_f32_fp8(sv, true);
        a0 = w * lo.x; a1 = w * lo.y; a2 = w * hi.x; a3 = w * hi.y;
    }

#define CONSU8(rr, vv)                                                        \
    _Pragma("unroll") for (int j = 0; j < 4; j++) {                           \
        float we = EDGE_W(rr[j]);                                             \
        f32x2 lo = __builtin_amdgcn_cvt_pk_f32_fp8(vv[j], false);             \
        f32x2 hi = __builtin_amdgcn_cvt_pk_f32_fp8(vv[j], true);              \
        a0 = fmaf(we, lo.x, a0);                                              \
        a1 = fmaf(we, lo.y, a1);                                              \
        a2 = fmaf(we, hi.x, a2);                                              \
        a3 = fmaf(we, hi.y, a3);                                              \
    }

    int k0 = beg + g;                                     // this group's first edge
    int cnt = (k0 < end) ? ((end - k0 + 1) >> 1) : 0;     // edges this group owns
    int nfull = cnt >> 2;
    unsigned int rrA[4], rrB[4];
    if (nfull > 0) {
#pragma unroll
        for (int j = 0; j < 4; j++) rrA[j] = csr[k0 + 2 * j];
        int it = 0;
        while (it + 2 <= nfull) {
            {
                unsigned int vv[4];
#pragma unroll
                for (int j = 0; j < 4; j++) vv[j] = sbase[(size_t)EDGE_S(rrA[j]) * 32];
#pragma unroll
                for (int j = 0; j < 4; j++) rrB[j] = csr[k0 + ((it + 1) << 3) + 2 * j];
                CONSU8(rrA, vv)
            }
            {
                unsigned int vv[4];
#pragma unroll
                for (int j = 0; j < 4; j++) vv[j] = sbase[(size_t)EDGE_S(rrB[j]) * 32];
                if (it + 2 < nfull) {
#pragma unroll
                    for (int j = 0; j < 4; j++) rrA[j] = csr[k0 + ((it + 2) << 3) + 2 * j];
                }
                CONSU8(rrB, vv)
            }
            it += 2;
        }
        if (it < nfull) {
            unsigned int vv[4];
#pragma unroll
            for (int j = 0; j < 4; j++) vv[j] = sbase[(size_t)EDGE_S(rrA[j]) * 32];
            CONSU8(rrA, vv)
        }
    }
    int t0 = nfull << 2;
    if (t0 < cnt) {
        unsigned int rrt[4], vv[4];
#pragma unroll
        for (int j = 0; j < 4; j++) {
            int t = t0 + j;
            rrt[j] = csr[t < cnt ? k0 + 2 * t : beg];
        }
#pragma unroll
        for (int j = 0; j < 4; j++) vv[j] = sbase[(size_t)EDGE_S(rrt[j]) * 32];
#pragma unroll
        for (int j = 0; j < 4; j++) {
            float we = (t0 + j < cnt) ? EDGE_W(rrt[j]) : 0.f;
            f32x2 lo = __builtin_amdgcn_cvt_pk_f32_fp8(vv[j], false);
            f32x2 hi = __builtin_amdgcn_cvt_pk_f32_fp8(vv[j], true);
            a0 = fmaf(we, lo.x, a0);
            a1 = fmaf(we, lo.y, a1);
            a2 = fmaf(we, hi.x, a2);
            a3 = fmaf(we, hi.y, a3);
        }
    }
#undef CONSU8
    a0 += __shfl_xor(a0, 32, 64);
    a1 += __shfl_xor(a1, 32, 64);
    a2 += __shfl_xor(a2, 32, 64);
    a3 += __shfl_xor(a3, 32, 64);
    if (lane < 32) {
        int m = lane >> 1, sb = 4 * (lane & 1);
        float av[4] = {a0, a1, a2, a3};
#pragma unroll
        for (int j = 0; j < 4; j++) {
            int L = (sb + j) * 16 + m;
            if (L >= 40 && L < 80) T2a[(size_t)i * 40 + (L - 40)] = f2bf(av[j]);
            else if (L >= 80 && L < 120) T8b[(size_t)i * 40 + (L - 80)] = pack_fp8x1(av[j]);
        }
    }
}

// ---------------- fused second-hop prop + log_softmax -----------------------
// 6 groups x 10 lanes, batch-of-4 per group + prefetch + masked final batch

__global__ __launch_bounds__(256) void lsm_prop_k(const unsigned short* __restrict__ Ub,
                                                  const unsigned short* __restrict__ T2a,
                                                  const unsigned char* __restrict__ T8b,
                                                  const int* __restrict__ rowptr,
                                                  const unsigned int* __restrict__ csr,
                                                  const float* __restrict__ dinv,
                                                  const float* __restrict__ b2,
                                                  float* __restrict__ out, int n) {
    int wave = threadIdx.x >> 6;
    int lane = threadIdx.x & 63;
    int i = blockIdx.x * 4 + wave;
    if (i >= n) return;
    int beg = rowptr[i], end = rowptr[i + 1];
    float di = dinv[i];
    int g = lane / 10;           // 0..6 (lanes 60..63 inactive)
    int c = lane - g * 10;       // 0..9
    bool act = lane < 60;
    const unsigned int* sb = (const unsigned int*)T8b + c;  // row stride 10 uints
    float a0 = 0.f, a1 = 0.f, a2 = 0.f, a3 = 0.f;
    if (lane < 10) {  // self term counted once (group 0)
        unsigned int sv = sb[(size_t)i * 10];
        float w = di * di;
        f32x2 lo = __builtin_amdgcn_cvt_pk_f32_fp8(sv, false);
        f32x2 hi = __builtin_amdgcn_cvt_pk_f32_fp8(sv, true);
        a0 = w * lo.x; a1 = w * lo.y; a2 = w * hi.x; a3 = w * hi.y;
    }

#define CONSLS(rr, vv)                                                        \
    _Pragma("unroll") for (int j = 0; j < 4; j++) {                           \
        float we = EDGE_W(rr[j]);                                             \
        f32x2 lo = __builtin_amdgcn_cvt_pk_f32_fp8(vv[j], false);             \
        f32x2 hi = __builtin_amdgcn_cvt_pk_f32_fp8(vv[j], true);              \
        a0 = fmaf(we, lo.x, a0);                                              \
        a1 = fmaf(we, lo.y, a1);                                              \
        a2 = fmaf(we, hi.x, a2);                                              \
        a3 = fmaf(we, hi.y, a3);                                              \
    }

    int k0 = beg + g;
    int cnt = (act && k0 < end) ? ((end - k0 + 5) / 6) : 0;  // edges this group owns
    int nfull = cnt >> 2;
    unsigned int rrA[4], rrB[4];
    if (nfull > 0) {
#pragma unroll
        for (int j = 0; j < 4; j++) rrA[j] = csr[k0 + 6 * j];
        int it = 0;
        while (it + 2 <= nfull) {
            {
                unsigned int vv[4];
#pragma unroll
                for (int j = 0; j < 4; j++) vv[j] = sb[(size_t)EDGE_S(rrA[j]) * 10];
#pragma unroll
                for (int j = 0; j < 4; j++) rrB[j] = csr[k0 + (it + 1) * 24 + 6 * j];
                CONSLS(rrA, vv)
            }
            {
                unsigned int vv[4];
#pragma unroll
                for (int j = 0; j < 4; j++) vv[j] = sb[(size_t)EDGE_S(rrB[j]) * 10];
                if (it + 2 < nfull) {
#pragma unroll
                    for (int j = 0; j < 4; j++) rrA[j] = csr[k0 + (it + 2) * 24 + 6 * j];
                }
                CONSLS(rrB, vv)
            }
            it += 2;
        }
        if (it < nfull) {
            unsigned int vv[4];
#pragma unroll
            for (int j = 0; j < 4; j++) vv[j] = sb[(size_t)EDGE_S(rrA[j]) * 10];
            CONSLS(rrA, vv)
        }
    }
    int t0 = nfull << 2;
    if (t0 < cnt) {
        unsigned int rrt[4], vv[4];
#pragma unroll
        for (int j = 0; j < 4; j++) {
            int t = t0 + j;
            rrt[j] = csr[t < cnt ? k0 + 6 * t : beg];
        }
#pragma unroll
        for (int j = 0; j < 4; j++) vv[j] = sb[(size_t)EDGE_S(rrt[j]) * 10];
#pragma unroll
        for (int j = 0; j < 4; j++) {
            float we = (t0 + j < cnt) ? EDGE_W(rrt[j]) : 0.f;
            f32x2 lo = __builtin_amdgcn_cvt_pk_f32_fp8(vv[j], false);
            f32x2 hi = __builtin_amdgcn_cvt_pk_f32_fp8(vv[j], true);
            a0 = fmaf(we, lo.x, a0);
            a1 = fmaf(we, lo.y, a1);
            a2 = fmaf(we, hi.x, a2);
            a3 = fmaf(we, hi.y, a3);
        }
    }
#undef CONSLS
    // reduce the 6 group partials into lanes 0..9 (results valid there only)
    float r0s = a0, r1s = a1, r2s = a2, r3s = a3;
#pragma unroll
    for (int g2 = 1; g2 < 6; g2++) {
        r0s += __shfl(a0, lane + 10 * g2, 64);
        r1s += __shfl(a1, lane + 10 * g2, 64);
        r2s += __shfl(a2, lane + 10 * g2, 64);
        r3s += __shfl(a3, lane + 10 * g2, 64);
    }
    // redistribute: lane j1=lane+64 needs col idx=j1-80 from lane idx>>2, comp idx&3
    int j1 = lane + 64;
    int idx = j1 - 80;
    int srcl = (idx < 0) ? 0 : (idx >> 2);
    float s0v = __shfl(r0s, srcl, 64);
    float s1v = __shfl(r1s, srcl, 64);
    float s2v = __shfl(r2s, srcl, 64);
    float s3v = __shfl(r3s, srcl, 64);
    int comp = idx & 3;
    float pv = (comp == 0) ? s0v : (comp == 1) ? s1v : (comp == 2) ? s2v : s3v;
    float v0, v1;
    {
        int j = lane;  // 0..63
        float v = (j >= 40) ? bf2f(T2a[(size_t)i * 40 + (j - 40)]) : bf2f(Ub[(size_t)i * L2WP + j]);
        v0 = v + b2[j];
    }
    if (j1 < 120) {
        float v = (j1 < 80) ? bf2f(T2a[(size_t)i * 40 + (j1 - 40)]) : pv;
        v1 = v + b2[j1];
    } else {
        v1 = -INFINITY;
    }
    float m = fmaxf(v0, v1);
    for (int off = 32; off; off >>= 1) m = fmaxf(m, __shfl_xor(m, off, 64));
    float s = expf(v0 - m) + ((j1 < 120) ? expf(v1 - m) : 0.f);
    for (int off = 32; off; off >>= 1) s += __shfl_xor(s, off, 64);
    float ls = logf(s) + m;
    out[(size_t)i * 120 + lane] = v0 - ls;
    if (j1 < 120) out[(size_t)i * 120 + j1] = v1 - ls;
}

// ---------------- launch ----------------

static inline size_t align256(size_t x) { return (x + 255) & ~(size_t)255; }

extern "C" void kernel_launch(void* const* d_in, const int* in_sizes, int n_in,
                              void* d_out, int out_size, void* d_ws, size_t ws_size,
                              hipStream_t stream) {
    const float* x = (const float*)d_in[0];
    const int* ei = (const int*)d_in[1];
    const float* W1_0 = (const float*)d_in[2];
    const float* W1_1 = (const float*)d_in[3];
    const float* W1_2 = (const float*)d_in[4];
    const float* b1 = (const float*)d_in[5];
    const float* W2_0 = (const float*)d_in[6];
    const float* W2_1 = (const float*)d_in[7];
    const float* W2_2 = (const float*)d_in[8];
    const float* b2 = (const float*)d_in[9];
    float* out = (float*)d_out;

    const int n = N_NODES;
    const int E = in_sizes[1] / 2;
    const int nb = (n + 255) / 256;
    const int n2 = NBUK * NBLK1;
    const int nb2 = (n2 + 255) / 256;

    char* p = (char*)d_ws;
    size_t off = 0;
    auto alloc = [&](size_t bytes) {
        void* r = p + off;
        off = align256(off + bytes);
        return r;
    };
    int* cnt = (int*)alloc((size_t)n * 4);
    int* rowptr = (int*)alloc((size_t)(n + 1) * 4);
    int* bsum = (int*)alloc((size_t)nb * 4);
    float* dinv = (float*)alloc((size_t)n * 4);
    unsigned int* csr = (unsigned int*)alloc((size_t)E * 4);
    int* cnt2 = (int*)alloc((size_t)n2 * 4);
    int* off2 = (int*)alloc((size_t)n2 * 4);
    int* bsum2 = (int*)alloc((size_t)nb2 * 4);
    int* tot2 = (int*)alloc(4);
    unsigned int* stage = (unsigned int*)alloc((size_t)E * 4);
    unsigned short* Bp1 = (unsigned short*)alloc((size_t)N1PACK * 2);
    unsigned short* Bp2 = (unsigned short*)alloc((size_t)N2PACK * 2);
    unsigned short* Hb = (unsigned short*)alloc((size_t)n * L1W * 2);
    unsigned char* Y8 = (unsigned char*)alloc((size_t)n * 256);
    unsigned char* T8 = (unsigned char*)alloc((size_t)n * 128);
    unsigned short* Ub = (unsigned short*)alloc((size_t)n * L2WP * 2);
    unsigned char* U8 = (unsigned char*)alloc((size_t)n * 128);
    unsigned short* T2a = (unsigned short*)alloc((size_t)n * C_OUT * 2);
    unsigned char* T8b = (unsigned char*)alloc((size_t)n * C_OUT);
    (void)ws_size;

    // 1. fused: per-node degree + bucket hist + weight pack (one pass)
    hipMemsetAsync(cnt, 0, (size_t)n * 4, stream);
    fhist_k<<<NBLK1 + PACKB, 256, 0, stream>>>(ei, W1_0, W1_1, W1_2, W2_0, W2_1, W2_2,
                                               cnt, cnt2, Bp1, Bp2, E);

    // 2. fused scans (node chain: rowptr+dinv; bucket chain: off2)
    fscan1_k<<<nb + nb2, 256, 0, stream>>>(cnt, bsum, n, cnt2, bsum2, n2, nb);
    fscan2_k<<<2, 256, 0, stream>>>(bsum, rowptr + n, nb, bsum2, tot2, nb2);
    fscan3_k<<<nb + nb2, 256, 0, stream>>>(cnt, bsum, rowptr, dinv, n,
                                           cnt2, bsum2, off2, n2, nb);

    // 3. binned stage, then FUSED scatter2 + layer-1 GEMM (scatter rides along)
    stage_k<<<NBLK1, 256, 0, stream>>>(ei, off2, stage, E);
    scmg1_k<<<NBUK + (n + 63) / 64, 256, 0, stream>>>(stage, off2, rowptr, dinv, csr, E,
                                                      x, Bp1, b1, Hb, Y8, n);

    // 4. layer-1 props (dual-row waves)
    prop256f_k<<<(n + 7) / 8, 256, 0, stream>>>(Y8, Hb, T8, rowptr, csr, dinv, b1, n);
    prop128f_k<<<(n + 7) / 8, 256, 0, stream>>>(T8, Hb, rowptr, csr, dinv, b1, n);

    // 5. layer 2 GEMM -> Ub bf16 (cols<48) + U8 fp8 (1 line/row)
    mgemm2_k<<<(n + 63) / 64, 256, 0, stream>>>(Hb, Bp2, Ub, U8, n);
    propU8_k<<<(n + 3) / 4, 256, 0, stream>>>(U8, T2a, T8b, rowptr, csr, dinv, n);

    // 6. fused second hop + log_softmax
    lsm_prop_k<<<(n + 3) / 4, 256, 0, stream>>>(Ub, T2a, T8b, rowptr, csr, dinv, b2, out, n);
}

// Round 14
// 319.521 us; speedup vs baseline: 1.0546x; 1.0546x over previous
//
#include <hip/hip_runtime.h>
#include <hip/hip_bf16.h>
#include <math.h>

#define N_NODES 50000
#define F_IN 256
#define H1 128
#define C_OUT 40
#define L1W 384   // 3*H1
#define L2W 120   // 3*C_OUT
#define L2WP 128  // padded
#define NBUK 196  // ceil(50000/256) dst buckets of 256 nodes
#define NBLK1 256 // phase-1 blocks

typedef __attribute__((ext_vector_type(8))) short short8;
typedef __attribute__((ext_vector_type(4))) float f32x4;
typedef __attribute__((ext_vector_type(2))) float f32x2;

typedef __attribute__((address_space(1))) const unsigned int gu32;
typedef __attribute__((address_space(3))) unsigned int lu32;

__device__ __forceinline__ void g2l16(const void* g, void* l) {
    __builtin_amdgcn_global_load_lds((gu32*)g, (lu32*)l, 16, 0, 0);
}

__device__ inline unsigned short f2bf(float f) {
    union { float f; unsigned int u; } x;
    x.f = f;
    unsigned int u = x.u;
    return (unsigned short)((u + 0x7FFF + ((u >> 16) & 1)) >> 16);
}
__device__ inline float bf2f(unsigned short u) {
    union { unsigned int u; float f; } x;
    x.u = (unsigned int)u << 16;
    return x.f;
}
__device__ inline unsigned int pack_fp8x4(float a, float b, float c, float d) {
    int v = 0;
    v = __builtin_amdgcn_cvt_pk_fp8_f32(a, b, v, false);  // bytes 0,1
    v = __builtin_amdgcn_cvt_pk_fp8_f32(c, d, v, true);   // bytes 2,3
    return (unsigned int)v;
}
__device__ inline unsigned short pack_fp8x2(float a, float b) {
    return (unsigned short)(__builtin_amdgcn_cvt_pk_fp8_f32(a, b, 0, false) & 0xFFFF);
}
__device__ inline unsigned char pack_fp8x1(float a) {
    return (unsigned char)(__builtin_amdgcn_cvt_pk_fp8_f32(a, a, 0, false) & 0xFF);
}
// decode 4B edge record {w:bf16:16 | src:16}
#define EDGE_S(r) ((int)((r) & 0xFFFFu))
#define EDGE_W(r) bf2f((unsigned short)((r) >> 16))

// ---------------- inline edge-index dtype detection (per-wave, no launch) ----

__device__ __forceinline__ bool detect_i32(const int* __restrict__ ei) {
    int lane = threadIdx.x & 63;
    int v = ei[2 * lane + 1] | ei[2 * (lane + 64) + 1] |
            ei[2 * (lane + 128) + 1] | ei[2 * (lane + 192) + 1];
    return __ballot(v != 0) != 0ULL;
}

// ---------------- fused: per-node hist + bucket hist + weight pack ----------

#define N1PACK ((F_IN / 32) * L1W * 32)
#define N2PACK ((L1W / 32) * L2WP * 32)
#define PACKB ((N1PACK + N2PACK + 255) / 256)

__global__ __launch_bounds__(256) void fhist_k(const int* __restrict__ ei,
                                               const float* __restrict__ w10,
                                               const float* __restrict__ w11,
                                               const float* __restrict__ w12,
                                               const float* __restrict__ w20,
                                               const float* __restrict__ w21,
                                               const float* __restrict__ w22,
                                               int* __restrict__ cnt,
                                               int* __restrict__ cnt2,
                                               unsigned short* __restrict__ Bp1,
                                               unsigned short* __restrict__ Bp2, int E) {
    __shared__ int lcnt[NBUK];
    int t = threadIdx.x, blk = blockIdx.x;
    if (blk < NBLK1) {
        bool i32 = detect_i32(ei);
        for (int j = t; j < NBUK; j += 256) lcnt[j] = 0;
        __syncthreads();
        int chunk = (E + NBLK1 - 1) / NBLK1;
        int beg = blk * chunk, end = min(beg + chunk, E);
        const long long* e64 = (const long long*)ei;
        for (int e = beg + t; e < end; e += 256) {
            int d = i32 ? ei[E + e] : (int)e64[E + e];
            atomicAdd(&cnt[d], 1);
            atomicAdd(&lcnt[d >> 8], 1);
        }
        __syncthreads();
        for (int j = t; j < NBUK; j += 256) cnt2[j * NBLK1 + blk] = lcnt[j];  // bucket-major
    } else {
        int idx = (blk - NBLK1) * 256 + t;
        if (idx < N1PACK) {
            int kt = idx / (L1W * 32);
            int tt = idx % (L1W * 32);
            int s = tt >> 9;
            int u = tt & 511;
            int kq = u >> 7, m = (u >> 3) & 15, kk = u & 7;
            int col = s * 16 + m;
            int k = kt * 32 + kq * 8 + kk;
            int p = col >> 7, c = col & 127;
            const float* w = (p == 0) ? w10 : (p == 1) ? w11 : w12;
            Bp1[idx] = f2bf(w[k * H1 + c]);
        } else if (idx < N1PACK + N2PACK) {
            int j = idx - N1PACK;
            int kt = j / (L2WP * 32);
            int tt = j % (L2WP * 32);
            int s = tt >> 9;
            int u = tt & 511;
            int kq = u >> 7, m = (u >> 3) & 15, kk = u & 7;
            int col = s * 16 + m;
            int k = kt * 32 + kq * 8 + kk;
            unsigned short v = 0;
            if (col < L2W) {
                int p = col / 40, c = col % 40;
                const float* w = (p == 0) ? w20 : (p == 1) ? w21 : w22;
                v = f2bf(w[k * C_OUT + c]);
            }
            Bp2[j] = v;
        }
    }
}

// ---------------- fused 3-level exclusive scans (node chain + bucket chain) --

__global__ __launch_bounds__(256) void fscan1_k(const int* __restrict__ cntA,
                                                int* __restrict__ bsumA, int nA,
                                                const int* __restrict__ cntB,
                                                int* __restrict__ bsumB, int nB, int nbA) {
    int b = blockIdx.x;
    const int* cnt;
    int* bsum;
    int n, bb;
    if (b < nbA) { cnt = cntA; bsum = bsumA; n = nA; bb = b; }
    else         { cnt = cntB; bsum = bsumB; n = nB; bb = b - nbA; }
    int t = threadIdx.x;
    int i = bb * 256 + t;
    int v = (i < n) ? cnt[i] : 0;
    for (int off = 32; off; off >>= 1) v += __shfl_down(v, off, 64);
    __shared__ int ws[4];
    if ((t & 63) == 0) ws[t >> 6] = v;
    __syncthreads();
    if (t == 0) bsum[bb] = ws[0] + ws[1] + ws[2] + ws[3];
}

__global__ __launch_bounds__(256) void fscan2_k(int* __restrict__ bsumA,
                                                int* __restrict__ btotA, int nbA,
                                                int* __restrict__ bsumB,
                                                int* __restrict__ btotB, int nbB) {
    int* bsum;
    int* btot;
    int nb;
    if (blockIdx.x == 0) { bsum = bsumA; btot = btotA; nb = nbA; }
    else                 { bsum = bsumB; btot = btotB; nb = nbB; }
    __shared__ int s[256];
    int t = threadIdx.x;
    int v = (t < nb) ? bsum[t] : 0;
    s[t] = v;
    __syncthreads();
    for (int off = 1; off < 256; off <<= 1) {
        int u = (t >= off) ? s[t - off] : 0;
        __syncthreads();
        s[t] += u;
        __syncthreads();
    }
    if (t < nb) bsum[t] = s[t] - v;  // exclusive
    if (t == nb - 1) *btot = s[t];
}

__global__ __launch_bounds__(256) void fscan3_k(const int* __restrict__ cntA,
                                                const int* __restrict__ bsumA,
                                                int* __restrict__ rpA,
                                                float* __restrict__ dinv, int nA,
                                                const int* __restrict__ cntB,
                                                const int* __restrict__ bsumB,
                                                int* __restrict__ rpB, int nB, int nbA) {
    int b = blockIdx.x;
    const int* cnt;
    const int* bsum;
    int* rowptr;
    float* dv;
    int n, bb;
    if (b < nbA) { cnt = cntA; bsum = bsumA; rowptr = rpA; dv = dinv; n = nA; bb = b; }
    else         { cnt = cntB; bsum = bsumB; rowptr = rpB; dv = nullptr; n = nB; bb = b - nbA; }
    __shared__ int s[256];
    int t = threadIdx.x;
    int i = bb * 256 + t;
    int v = (i < n) ? cnt[i] : 0;
    s[t] = v;
    __syncthreads();
    for (int off = 1; off < 256; off <<= 1) {
        int u = (t >= off) ? s[t - off] : 0;
        __syncthreads();
        s[t] += u;
        __syncthreads();
    }
    if (i < n) {
        rowptr[i] = s[t] - v + bsum[bb];
        if (dv) dv[i] = rsqrtf((float)v + 1.0f);
    }
}

// ---------------- binned stage (phase 1 of scatter) -------------------------

__global__ __launch_bounds__(256) void stage_k(const int* __restrict__ ei,
                                               const int* __restrict__ off2,
                                               unsigned int* __restrict__ stage, int E) {
    __shared__ int lcur[NBUK];
    bool i32 = detect_i32(ei);
    int t = threadIdx.x, blk = blockIdx.x;
    for (int j = t; j < NBUK; j += 256) lcur[j] = off2[j * NBLK1 + blk];
    __syncthreads();
    int chunk = (E + NBLK1 - 1) / NBLK1;
    int beg = blk * chunk, end = min(beg + chunk, E);
    const long long* e64 = (const long long*)ei;
    for (int e = beg + t; e < end; e += 256) {
        int s, d;
        if (i32) { s = ei[e]; d = ei[E + e]; }
        else { s = (int)e64[e]; d = (int)e64[E + e]; }
        int b = d >> 8;
        int pos = atomicAdd(&lcur[b], 1);
        stage[pos] = ((unsigned int)(d & 255) << 16) | (unsigned int)s;
    }
}

// ---------------- FUSED: scatter2 (blocks 0..NBUK) + layer-1 GEMM -----------
// GEMM: counted-vmcnt pipeline, raw barriers, (256,3): LDS 50176*3 <= 160KB.

__global__ __launch_bounds__(256, 3) void scmg1_k(const unsigned int* __restrict__ stage,
                                                  const int* __restrict__ off2,
                                                  const int* __restrict__ rowptr,
                                                  const float* __restrict__ dinv,
                                                  unsigned int* __restrict__ csr, int E,
                                                  const float* __restrict__ A,
                                                  const unsigned short* __restrict__ Bp,
                                                  const float* __restrict__ b1,
                                                  unsigned short* __restrict__ Hb,
                                                  unsigned char* __restrict__ Y8, int N) {
    __shared__ unsigned short Bls[2][L1W * 32];  // 2 slots x 24 KB (GEMM)
    __shared__ int lfill[256];                   // scatter
    int tid = threadIdx.x;
    if (blockIdx.x < NBUK) {
        // ---- scatter2 body ----
        int b = blockIdx.x, t = tid;
        int node0 = b << 8;
        int node = node0 + t;
        lfill[t] = (node < N) ? rowptr[node] : 0;
        __syncthreads();
        int segBeg = off2[b * NBLK1];
        int segEnd = (b == NBUK - 1) ? E : off2[(b + 1) * NBLK1];
        for (int e = segBeg + t; e < segEnd; e += 256) {
            unsigned int rec = stage[e];
            int dl = rec >> 16;
            int s = rec & 0xFFFF;
            int d = node0 + dl;
            float w = dinv[s] * dinv[d];
            int pos = atomicAdd(&lfill[dl], 1);
            csr[pos] = ((unsigned int)f2bf(w) << 16) | (unsigned int)s;
        }
        return;
    }
    // ---- mgemm1 body ----
    int w = tid >> 6, lane = tid & 63;
    int m = lane & 15, kq = lane >> 4;
    int row0 = (blockIdx.x - NBUK) * 64 + w * 16;
    int arow = row0 + m;
    if (arow >= N) arow = N - 1;  // clamped duplicate; stores guarded
    const float* Ap = A + (size_t)arow * F_IN + kq * 8;
    const char* srcb = (const char*)Bp + (size_t)(w * 6) * 1024 + (size_t)lane * 16;

    float4 at0[8], at1[8];
#pragma unroll
    for (int kt = 0; kt < 8; kt++) {
        at0[kt] = *(const float4*)(Ap + kt * 32);
        at1[kt] = *(const float4*)(Ap + kt * 32 + 4);
    }
#pragma unroll
    for (int j = 0; j < 6; j++) g2l16(srcb + j * 1024, &Bls[0][(w * 6 + j) * 512]);
#pragma unroll
    for (int j = 0; j < 6; j++) g2l16(srcb + 24576 + j * 1024, &Bls[1][(w * 6 + j) * 512]);
    short8 areg[8];
#pragma unroll
    for (int kt = 0; kt < 8; kt++) {
        float4 u = at0[kt], v = at1[kt];
        short8 a;
        a[0] = (short)f2bf(u.x); a[1] = (short)f2bf(u.y);
        a[2] = (short)f2bf(u.z); a[3] = (short)f2bf(u.w);
        a[4] = (short)f2bf(v.x); a[5] = (short)f2bf(v.y);
        a[6] = (short)f2bf(v.z); a[7] = (short)f2bf(v.w);
        areg[kt] = a;
    }

    f32x4 acc[24];
#pragma unroll
    for (int s = 0; s < 24; s++) acc[s] = (f32x4){0.f, 0.f, 0.f, 0.f};

#pragma unroll
    for (int kt = 0; kt < 8; kt++) {
        if (kt < 7) { asm volatile("s_waitcnt vmcnt(6)" ::: "memory"); }
        else        { asm volatile("s_waitcnt vmcnt(0)" ::: "memory"); }
        __builtin_amdgcn_s_barrier();
        __builtin_amdgcn_sched_barrier(0);
        const unsigned short* Bbuf = Bls[kt & 1];
        __builtin_amdgcn_s_setprio(1);
#pragma unroll
        for (int c = 0; c < 4; c++) {
            short8 bf[6];
#pragma unroll
            for (int j = 0; j < 6; j++)
                bf[j] = *(const short8*)(&Bbuf[(c * 6 + j) * 512 + lane * 8]);
#pragma unroll
            for (int j = 0; j < 6; j++)
                acc[c * 6 + j] = __builtin_amdgcn_mfma_f32_16x16x32_bf16(
                    areg[kt], bf[j], acc[c * 6 + j], 0, 0, 0);
        }
        __builtin_amdgcn_s_setprio(0);
        asm volatile("s_waitcnt lgkmcnt(0)" ::: "memory");  // reads retired
        __builtin_amdgcn_s_barrier();                       // slot kt reusable
        if (kt < 6) {
#pragma unroll
            for (int j = 0; j < 6; j++)
                g2l16(srcb + (size_t)(kt + 2) * 24576 + j * 1024,
                      &Bls[kt & 1][(w * 6 + j) * 512]);
        }
    }

    int crow = row0 + kq * 4;
#pragma unroll
    for (int s = 0; s < 8; s++) {
        int col = s * 16 + m;
        float bias = b1[col];
#pragma unroll
        for (int r2 = 0; r2 < 4; r2++) {
            int row = crow + r2;
            if (row < N) Hb[(size_t)row * L1W + col] = f2bf(fmaxf(acc[s][r2] + bias, 0.f));
        }
    }
#pragma unroll
    for (int r2 = 0; r2 < 4; r2++) {
        int row = crow + r2;
        if (row < N) {
            uint4 u;
            u.x = pack_fp8x4(acc[8][r2], acc[9][r2], acc[10][r2], acc[11][r2]);
            u.y = pack_fp8x4(acc[12][r2], acc[13][r2], acc[14][r2], acc[15][r2]);
            u.z = pack_fp8x4(acc[16][r2], acc[17][r2], acc[18][r2], acc[19][r2]);
            u.w = pack_fp8x4(acc[20][r2], acc[21][r2], acc[22][r2], acc[23][r2]);
            *(uint4*)(Y8 + (size_t)row * 256 + m * 16) = u;
        }
    }
}

// ---------------- layer-2 GEMM: counted-vmcnt structure ---------------------

__global__ __launch_bounds__(256, 3) void mgemm2_k(const unsigned short* __restrict__ A,
                                                   const unsigned short* __restrict__ Bp,
                                                   unsigned short* __restrict__ Ub,
                                                   unsigned char* __restrict__ U8, int N) {
    __shared__ unsigned short Bls[2][L2WP * 32];  // 2 slots x 8 KB
    int tid = threadIdx.x;
    int w = tid >> 6, lane = tid & 63;
    int m = lane & 15, kq = lane >> 4;
    int row0 = blockIdx.x * 64 + w * 16;
    int arow = row0 + m;
    if (arow >= N) arow = N - 1;
    const unsigned short* Ap = A + (size_t)arow * L1W + kq * 8;
    const char* srcb = (const char*)Bp + (size_t)(w * 2) * 1024 + (size_t)lane * 16;

    short8 areg[12];
#pragma unroll
    for (int kt = 0; kt < 12; kt++) areg[kt] = *(const short8*)(Ap + kt * 32);
#pragma unroll
    for (int j = 0; j < 2; j++) g2l16(srcb + j * 1024, &Bls[0][(w * 2 + j) * 512]);
#pragma unroll
    for (int j = 0; j < 2; j++) g2l16(srcb + 8192 + j * 1024, &Bls[1][(w * 2 + j) * 512]);

    f32x4 acc[8];
#pragma unroll
    for (int s = 0; s < 8; s++) acc[s] = (f32x4){0.f, 0.f, 0.f, 0.f};

#pragma unroll
    for (int kt = 0; kt < 12; kt++) {
        if (kt < 11) { asm volatile("s_waitcnt vmcnt(2)" ::: "memory"); }
        else         { asm volatile("s_waitcnt vmcnt(0)" ::: "memory"); }
        __builtin_amdgcn_s_barrier();
        __builtin_amdgcn_sched_barrier(0);
        const unsigned short* Bbuf = Bls[kt & 1];
        __builtin_amdgcn_s_setprio(1);
        short8 bf[8];
#pragma unroll
        for (int j = 0; j < 8; j++)
            bf[j] = *(const short8*)(&Bbuf[j * 512 + lane * 8]);
#pragma unroll
        for (int j = 0; j < 8; j++)
            acc[j] = __builtin_amdgcn_mfma_f32_16x16x32_bf16(areg[kt], bf[j], acc[j], 0, 0, 0);
        __builtin_amdgcn_s_setprio(0);
        asm volatile("s_waitcnt lgkmcnt(0)" ::: "memory");
        __builtin_amdgcn_s_barrier();
        if (kt < 10) {
#pragma unroll
            for (int j = 0; j < 2; j++)
                g2l16(srcb + (size_t)(kt + 2) * 8192 + j * 1024,
                      &Bls[kt & 1][(w * 2 + j) * 512]);
        }
    }

    int crow = row0 + kq * 4;
#pragma unroll
    for (int s = 0; s < 3; s++) {
        int col = s * 16 + m;
#pragma unroll
        for (int r2 = 0; r2 < 4; r2++) {
            int row = crow + r2;
            if (row < N) Ub[(size_t)row * L2WP + col] = f2bf(acc[s][r2]);
        }
    }
#pragma unroll
    for (int r2 = 0; r2 < 4; r2++) {
        int row = crow + r2;
        if (row < N) {
            uint2 u;
            u.x = pack_fp8x4(acc[0][r2], acc[1][r2], acc[2][r2], acc[3][r2]);
            u.y = pack_fp8x4(acc[4][r2], acc[5][r2], acc[6][r2], acc[7][r2]);
            *(uint2*)(U8 + (size_t)row * 128 + m * 8) = u;
        }
    }
}

// ---------------- fused width-256 fp8 prop over Y8 --------------------------
// pipelined: ping-pong csr prefetch (rrA/rrB) + masked final batch (no serial tail)

__global__ __launch_bounds__(256) void prop256f_k(const unsigned char* __restrict__ Y8,
                                                  unsigned short* __restrict__ Hb,
                                                  unsigned char* __restrict__ T8,
                                                  const int* __restrict__ rowptr,
                                                  const unsigned int* __restrict__ csr,
                                                  const float* __restrict__ dinv,
                                                  const float* __restrict__ b1, int n) {
    int wave = threadIdx.x >> 6, lane = threadIdx.x & 63;
    int i = blockIdx.x * 4 + wave;
    if (i >= n) return;
    int beg = rowptr[i], end = rowptr[i + 1];
    float di = dinv[i];
    const unsigned int* sbase = (const unsigned int*)Y8 + lane;  // row stride 64 uints
    unsigned int sv = sbase[(size_t)i * 64];
    float w = di * di;
    f32x2 slo = __builtin_amdgcn_cvt_pk_f32_fp8(sv, false);
    f32x2 shi = __builtin_amdgcn_cvt_pk_f32_fp8(sv, true);
    float a0 = w * slo.x, a1 = w * slo.y, a2 = w * shi.x, a3 = w * shi.y;

#define CONS256(rr, vv)                                                       \
    _Pragma("unroll") for (int e = 0; e < 8; e++) {                           \
        float we = EDGE_W(rr[e]);                                             \
        f32x2 lo = __builtin_amdgcn_cvt_pk_f32_fp8(vv[e], false);             \
        f32x2 hi = __builtin_amdgcn_cvt_pk_f32_fp8(vv[e], true);              \
        a0 = fmaf(we, lo.x, a0);                                              \
        a1 = fmaf(we, lo.y, a1);                                              \
        a2 = fmaf(we, hi.x, a2);                                              \
        a3 = fmaf(we, hi.y, a3);                                              \
    }

    int nfull = (end - beg) >> 3;
    unsigned int rrA[8], rrB[8];
    if (nfull > 0) {
#pragma unroll
        for (int e = 0; e < 8; e++) rrA[e] = csr[beg + e];
        int it = 0;
        while (it + 2 <= nfull) {
            {
                unsigned int vv[8];
#pragma unroll
                for (int e = 0; e < 8; e++) vv[e] = sbase[(size_t)EDGE_S(rrA[e]) * 64];
#pragma unroll
                for (int e = 0; e < 8; e++) rrB[e] = csr[beg + ((it + 1) << 3) + e];
                CONS256(rrA, vv)
            }
            {
                unsigned int vv[8];
#pragma unroll
                for (int e = 0; e < 8; e++) vv[e] = sbase[(size_t)EDGE_S(rrB[e]) * 64];
                if (it + 2 < nfull) {
#pragma unroll
                    for (int e = 0; e < 8; e++) rrA[e] = csr[beg + ((it + 2) << 3) + e];
                }
                CONS256(rrB, vv)
            }
            it += 2;
        }
        if (it < nfull) {  // odd last full batch (in rrA)
            unsigned int vv[8];
#pragma unroll
            for (int e = 0; e < 8; e++) vv[e] = sbase[(size_t)EDGE_S(rrA[e]) * 64];
            CONS256(rrA, vv)
        }
    }
    int k = beg + (nfull << 3);
    if (k < end) {  // masked final batch: parallel loads, zeroed weights OOB
        unsigned int rrt[8];
#pragma unroll
        for (int e = 0; e < 8; e++) {
            int idx = k + e;
            rrt[e] = csr[idx < end ? idx : beg];
        }
        unsigned int vv[8];
#pragma unroll
        for (int e = 0; e < 8; e++) vv[e] = sbase[(size_t)EDGE_S(rrt[e]) * 64];
#pragma unroll
        for (int e = 0; e < 8; e++) {
            float we = (k + e < end) ? EDGE_W(rrt[e]) : 0.f;
            f32x2 lo = __builtin_amdgcn_cvt_pk_f32_fp8(vv[e], false);
            f32x2 hi = __builtin_amdgcn_cvt_pk_f32_fp8(vv[e], true);
            a0 = fmaf(we, lo.x, a0);
            a1 = fmaf(we, lo.y, a1);
            a2 = fmaf(we, hi.x, a2);
            a3 = fmaf(we, hi.y, a3);
        }
    }
#undef CONS256
    int m = lane >> 2, jj = lane & 3;
    if (jj < 2) {  // z1: logical cols L_j = (4*jj+j)*16 + m
        float av[4] = {a0, a1, a2, a3};
#pragma unroll
        for (int j = 0; j < 4; j++) {
            int L = (4 * jj + j) * 16 + m;
            Hb[(size_t)i * L1W + 128 + L] = f2bf(fmaxf(av[j] + b1[128 + L], 0.f));
        }
    } else {       // t2 -> T8 phys = m*8 + 4*(jj-2)
        unsigned int o = pack_fp8x4(a0, a1, a2, a3);
        *(unsigned int*)(T8 + (size_t)i * 128 + m * 8 + 4 * (jj - 2)) = o;
    }
}

// ---------------- width-128 fp8 prop: Hb[:,256:384] = relu(P(T8)+b1) --------

__global__ __launch_bounds__(256) void prop128f_k(const unsigned char* __restrict__ T8,
                                                  unsigned short* __restrict__ Hb,
                                                  const int* __restrict__ rowptr,
                                                  const unsigned int* __restrict__ csr,
                                                  const float* __restrict__ dinv,
                                                  const float* __restrict__ b1, int n) {
    int wave = threadIdx.x >> 6, lane = threadIdx.x & 63;
    int i = blockIdx.x * 4 + wave;
    if (i >= n) return;
    int beg = rowptr[i], end = rowptr[i + 1];
    float di = dinv[i];
    const unsigned short* sbase = (const unsigned short*)T8 + lane;  // row stride 64
    unsigned int sv = sbase[(size_t)i * 64];
    float w = di * di;
    f32x2 sd = __builtin_amdgcn_cvt_pk_f32_fp8(sv, false);
    float a0 = w * sd.x, a1 = w * sd.y;

#define CONS128(rr, vv)                                                       \
    _Pragma("unroll") for (int e = 0; e < 8; e++) {                           \
        float we = EDGE_W(rr[e]);                                             \
        f32x2 d = __builtin_amdgcn_cvt_pk_f32_fp8(vv[e], false);              \
        a0 = fmaf(we, d.x, a0);                                               \
        a1 = fmaf(we, d.y, a1);                                               \
    }

    int nfull = (end - beg) >> 3;
    unsigned int rrA[8], rrB[8];
    if (nfull > 0) {
#pragma unroll
        for (int e = 0; e < 8; e++) rrA[e] = csr[beg + e];
        int it = 0;
        while (it + 2 <= nfull) {
            {
                unsigned int vv[8];
#pragma unroll
                for (int e = 0; e < 8; e++) vv[e] = sbase[(size_t)EDGE_S(rrA[e]) * 64];
#pragma unroll
                for (int e = 0; e < 8; e++) rrB[e] = csr[beg + ((it + 1) << 3) + e];
                CONS128(rrA, vv)
            }
            {
                unsigned int vv[8];
#pragma unroll
                for (int e = 0; e < 8; e++) vv[e] = sbase[(size_t)EDGE_S(rrB[e]) * 64];
                if (it + 2 < nfull) {
#pragma unroll
                    for (int e = 0; e < 8; e++) rrA[e] = csr[beg + ((it + 2) << 3) + e];
                }
                CONS128(rrB, vv)
            }
            it += 2;
        }
        if (it < nfull) {
            unsigned int vv[8];
#pragma unroll
            for (int e = 0; e < 8; e++) vv[e] = sbase[(size_t)EDGE_S(rrA[e]) * 64];
            CONS128(rrA, vv)
        }
    }
    int k = beg + (nfull << 3);
    if (k < end) {
        unsigned int rrt[8];
#pragma unroll
        for (int e = 0; e < 8; e++) {
            int idx = k + e;
            rrt[e] = csr[idx < end ? idx : beg];
        }
        unsigned int vv[8];
#pragma unroll
        for (int e = 0; e < 8; e++) vv[e] = sbase[(size_t)EDGE_S(rrt[e]) * 64];
#pragma unroll
        for (int e = 0; e < 8; e++) {
            float we = (k + e < end) ? EDGE_W(rrt[e]) : 0.f;
            f32x2 d = __builtin_amdgcn_cvt_pk_f32_fp8(vv[e], false);
            a0 = fmaf(we, d.x, a0);
            a1 = fmaf(we, d.y, a1);
        }
    }
#undef CONS128
    int m = lane >> 2, u0 = (2 * lane) & 7;
    int L0 = u0 * 16 + m, L1 = (u0 + 1) * 16 + m;
    Hb[(size_t)i * L1W + 256 + L0] = f2bf(fmaxf(a0 + b1[256 + L0], 0.f));
    Hb[(size_t)i * L1W + 256 + L1] = f2bf(fmaxf(a1 + b1[256 + L1], 0.f));
}

// ---------------- layer-2 prop over U8: 2 edge-groups x 32 cols -------------
// batch-of-4 per group + csr ping-pong prefetch + masked final batch

__global__ __launch_bounds__(256) void propU8_k(const unsigned char* __restrict__ U8,
                                                unsigned short* __restrict__ T2a,
                                                unsigned char* __restrict__ T8b,
                                                const int* __restrict__ rowptr,
                                                const unsigned int* __restrict__ csr,
                                                const float* __restrict__ dinv, int n) {
    int wave = threadIdx.x >> 6, lane = threadIdx.x & 63;
    int i = blockIdx.x * 4 + wave;
    if (i >= n) return;
    int beg = rowptr[i], end = rowptr[i + 1];
    float di = dinv[i];
    int g = lane >> 5, c = lane & 31;
    const unsigned int* sbase = (const unsigned int*)U8 + c;  // row stride 32 uints
    float a0 = 0.f, a1 = 0.f, a2 = 0.f, a3 = 0.f;
    if (g == 0) {
        unsigned int sv = sbase[(size_t)i * 32];
        float w = di * di;
        f32x2 lo = __builtin_amdgcn_cvt_pk_f32_fp8(sv, false);
        f32x2 hi = __builtin_amdgcn_cvt_pk_f32_fp8(sv, true);
        a0 = w * lo.x; a1 = w * lo.y; a2 = w * hi.x; a3 = w * hi.y;
    }

#define CONSU8(rr, vv)                                                        \
    _Pragma("unroll") for (int j = 0; j < 4; j++) {                           \
        float we = EDGE_W(rr[j]);                                             \
        f32x2 lo = __builtin_amdgcn_cvt_pk_f32_fp8(vv[j], false);             \
        f32x2 hi = __builtin_amdgcn_cvt_pk_f32_fp8(vv[j], true);              \
        a0 = fmaf(we, lo.x, a0);                                              \
        a1 = fmaf(we, lo.y, a1);                                              \
        a2 = fmaf(we, hi.x, a2);                                              \
        a3 = fmaf(we, hi.y, a3);                                              \
    }

    int k0 = beg + g;                                     // this group's first edge
    int cnt = (k0 < end) ? ((end - k0 + 1) >> 1) : 0;     // edges this group owns
    int nfull = cnt >> 2;
    unsigned int rrA[4], rrB[4];
    if (nfull > 0) {
#pragma unroll
        for (int j = 0; j < 4; j++) rrA[j] = csr[k0 + 2 * j];
        int it = 0;
        while (it + 2 <= nfull) {
            {
                unsigned int vv[4];
#pragma unroll
                for (int j = 0; j < 4; j++) vv[j] = sbase[(size_t)EDGE_S(rrA[j]) * 32];
#pragma unroll
                for (int j = 0; j < 4; j++) rrB[j] = csr[k0 + ((it + 1) << 3) + 2 * j];
                CONSU8(rrA, vv)
            }
            {
                unsigned int vv[4];
#pragma unroll
                for (int j = 0; j < 4; j++) vv[j] = sbase[(size_t)EDGE_S(rrB[j]) * 32];
                if (it + 2 < nfull) {
#pragma unroll
                    for (int j = 0; j < 4; j++) rrA[j] = csr[k0 + ((it + 2) << 3) + 2 * j];
                }
                CONSU8(rrB, vv)
            }
            it += 2;
        }
        if (it < nfull) {
            unsigned int vv[4];
#pragma unroll
            for (int j = 0; j < 4; j++) vv[j] = sbase[(size_t)EDGE_S(rrA[j]) * 32];
            CONSU8(rrA, vv)
        }
    }
    int t0 = nfull << 2;
    if (t0 < cnt) {
        unsigned int rrt[4], vv[4];
#pragma unroll
        for (int j = 0; j < 4; j++) {
            int t = t0 + j;
            rrt[j] = csr[t < cnt ? k0 + 2 * t : beg];
        }
#pragma unroll
        for (int j = 0; j < 4; j++) vv[j] = sbase[(size_t)EDGE_S(rrt[j]) * 32];
#pragma unroll
        for (int j = 0; j < 4; j++) {
            float we = (t0 + j < cnt) ? EDGE_W(rrt[j]) : 0.f;
            f32x2 lo = __builtin_amdgcn_cvt_pk_f32_fp8(vv[j], false);
            f32x2 hi = __builtin_amdgcn_cvt_pk_f32_fp8(vv[j], true);
            a0 = fmaf(we, lo.x, a0);
            a1 = fmaf(we, lo.y, a1);
            a2 = fmaf(we, hi.x, a2);
            a3 = fmaf(we, hi.y, a3);
        }
    }
#undef CONSU8
    a0 += __shfl_xor(a0, 32, 64);
    a1 += __shfl_xor(a1, 32, 64);
    a2 += __shfl_xor(a2, 32, 64);
    a3 += __shfl_xor(a3, 32, 64);
    if (lane < 32) {
        int m = lane >> 1, sb = 4 * (lane & 1);
        float av[4] = {a0, a1, a2, a3};
#pragma unroll
        for (int j = 0; j < 4; j++) {
            int L = (sb + j) * 16 + m;
            if (L >= 40 && L < 80) T2a[(size_t)i * 40 + (L - 40)] = f2bf(av[j]);
            else if (L >= 80 && L < 120) T8b[(size_t)i * 40 + (L - 80)] = pack_fp8x1(av[j]);
        }
    }
}

// ---------------- fused second-hop prop + log_softmax -----------------------
// 6 groups x 10 lanes, batch-of-4 per group + prefetch + masked final batch

__global__ __launch_bounds__(256) void lsm_prop_k(const unsigned short* __restrict__ Ub,
                                                  const unsigned short* __restrict__ T2a,
                                                  const unsigned char* __restrict__ T8b,
                                                  const int* __restrict__ rowptr,
                                                  const unsigned int* __restrict__ csr,
                                                  const float* __restrict__ dinv,
                                                  const float* __restrict__ b2,
                                                  float* __restrict__ out, int n) {
    int wave = threadIdx.x >> 6;
    int lane = threadIdx.x & 63;
    int i = blockIdx.x * 4 + wave;
    if (i >= n) return;
    int beg = rowptr[i], end = rowptr[i + 1];
    float di = dinv[i];
    int g = lane / 10;           // 0..6 (lanes 60..63 inactive)
    int c = lane - g * 10;       // 0..9
    bool act = lane < 60;
    const unsigned int* sb = (const unsigned int*)T8b + c;  // row stride 10 uints
    float a0 = 0.f, a1 = 0.f, a2 = 0.f, a3 = 0.f;
    if (lane < 10) {  // self term counted once (group 0)
        unsigned int sv = sb[(size_t)i * 10];
        float w = di * di;
        f32x2 lo = __builtin_amdgcn_cvt_pk_f32_fp8(sv, false);
        f32x2 hi = __builtin_amdgcn_cvt_pk_f32_fp8(sv, true);
        a0 = w * lo.x; a1 = w * lo.y; a2 = w * hi.x; a3 = w * hi.y;
    }

#define CONSLS(rr, vv)                                                        \
    _Pragma("unroll") for (int j = 0; j < 4; j++) {                           \
        float we = EDGE_W(rr[j]);                                             \
        f32x2 lo = __builtin_amdgcn_cvt_pk_f32_fp8(vv[j], false);             \
        f32x2 hi = __builtin_amdgcn_cvt_pk_f32_fp8(vv[j], true);              \
        a0 = fmaf(we, lo.x, a0);                                              \
        a1 = fmaf(we, lo.y, a1);                                              \
        a2 = fmaf(we, hi.x, a2);                                              \
        a3 = fmaf(we, hi.y, a3);                                              \
    }

    int k0 = beg + g;
    int cnt = (act && k0 < end) ? ((end - k0 + 5) / 6) : 0;  // edges this group owns
    int nfull = cnt >> 2;
    unsigned int rrA[4], rrB[4];
    if (nfull > 0) {
#pragma unroll
        for (int j = 0; j < 4; j++) rrA[j] = csr[k0 + 6 * j];
        int it = 0;
        while (it + 2 <= nfull) {
            {
                unsigned int vv[4];
#pragma unroll
                for (int j = 0; j < 4; j++) vv[j] = sb[(size_t)EDGE_S(rrA[j]) * 10];
#pragma unroll
                for (int j = 0; j < 4; j++) rrB[j] = csr[k0 + (it + 1) * 24 + 6 * j];
                CONSLS(rrA, vv)
            }
            {
                unsigned int vv[4];
#pragma unroll
                for (int j = 0; j < 4; j++) vv[j] = sb[(size_t)EDGE_S(rrB[j]) * 10];
                if (it + 2 < nfull) {
#pragma unroll
                    for (int j = 0; j < 4; j++) rrA[j] = csr[k0 + (it + 2) * 24 + 6 * j];
                }
                CONSLS(rrB, vv)
            }
            it += 2;
        }
        if (it < nfull) {
            unsigned int vv[4];
#pragma unroll
            for (int j = 0; j < 4; j++) vv[j] = sb[(size_t)EDGE_S(rrA[j]) * 10];
            CONSLS(rrA, vv)
        }
    }
    int t0 = nfull << 2;
    if (t0 < cnt) {
        unsigned int rrt[4], vv[4];
#pragma unroll
        for (int j = 0; j < 4; j++) {
            int t = t0 + j;
            rrt[j] = csr[t < cnt ? k0 + 6 * t : beg];
        }
#pragma unroll
        for (int j = 0; j < 4; j++) vv[j] = sb[(size_t)EDGE_S(rrt[j]) * 10];
#pragma unroll
        for (int j = 0; j < 4; j++) {
            float we = (t0 + j < cnt) ? EDGE_W(rrt[j]) : 0.f;
            f32x2 lo = __builtin_amdgcn_cvt_pk_f32_fp8(vv[j], false);
            f32x2 hi = __builtin_amdgcn_cvt_pk_f32_fp8(vv[j], true);
            a0 = fmaf(we, lo.x, a0);
            a1 = fmaf(we, lo.y, a1);
            a2 = fmaf(we, hi.x, a2);
            a3 = fmaf(we, hi.y, a3);
        }
    }
#undef CONSLS
    // reduce the 6 group partials into lanes 0..9 (results valid there only)
    float r0s = a0, r1s = a1, r2s = a2, r3s = a3;
#pragma unroll
    for (int g2 = 1; g2 < 6; g2++) {
        r0s += __shfl(a0, lane + 10 * g2, 64);
        r1s += __shfl(a1, lane + 10 * g2, 64);
        r2s += __shfl(a2, lane + 10 * g2, 64);
        r3s += __shfl(a3, lane + 10 * g2, 64);
    }
    // redistribute: lane j1=lane+64 needs col idx=j1-80 from lane idx>>2, comp idx&3
    int j1 = lane + 64;
    int idx = j1 - 80;
    int srcl = (idx < 0) ? 0 : (idx >> 2);
    float s0v = __shfl(r0s, srcl, 64);
    float s1v = __shfl(r1s, srcl, 64);
    float s2v = __shfl(r2s, srcl, 64);
    float s3v = __shfl(r3s, srcl, 64);
    int comp = idx & 3;
    float pv = (comp == 0) ? s0v : (comp == 1) ? s1v : (comp == 2) ? s2v : s3v;
    float v0, v1;
    {
        int j = lane;  // 0..63
        float v = (j >= 40) ? bf2f(T2a[(size_t)i * 40 + (j - 40)]) : bf2f(Ub[(size_t)i * L2WP + j]);
        v0 = v + b2[j];
    }
    if (j1 < 120) {
        float v = (j1 < 80) ? bf2f(T2a[(size_t)i * 40 + (j1 - 40)]) : pv;
        v1 = v + b2[j1];
    } else {
        v1 = -INFINITY;
    }
    float m = fmaxf(v0, v1);
    for (int off = 32; off; off >>= 1) m = fmaxf(m, __shfl_xor(m, off, 64));
    float s = expf(v0 - m) + ((j1 < 120) ? expf(v1 - m) : 0.f);
    for (int off = 32; off; off >>= 1) s += __shfl_xor(s, off, 64);
    float ls = logf(s) + m;
    out[(size_t)i * 120 + lane] = v0 - ls;
    if (j1 < 120) out[(size_t)i * 120 + j1] = v1 - ls;
}

// ---------------- launch ----------------

static inline size_t align256(size_t x) { return (x + 255) & ~(size_t)255; }

extern "C" void kernel_launch(void* const* d_in, const int* in_sizes, int n_in,
                              void* d_out, int out_size, void* d_ws, size_t ws_size,
                              hipStream_t stream) {
    const float* x = (const float*)d_in[0];
    const int* ei = (const int*)d_in[1];
    const float* W1_0 = (const float*)d_in[2];
    const float* W1_1 = (const float*)d_in[3];
    const float* W1_2 = (const float*)d_in[4];
    const float* b1 = (const float*)d_in[5];
    const float* W2_0 = (const float*)d_in[6];
    const float* W2_1 = (const float*)d_in[7];
    const float* W2_2 = (const float*)d_in[8];
    const float* b2 = (const float*)d_in[9];
    float* out = (float*)d_out;

    const int n = N_NODES;
    const int E = in_sizes[1] / 2;
    const int nb = (n + 255) / 256;
    const int n2 = NBUK * NBLK1;
    const int nb2 = (n2 + 255) / 256;

    char* p = (char*)d_ws;
    size_t off = 0;
    auto alloc = [&](size_t bytes) {
        void* r = p + off;
        off = align256(off + bytes);
        return r;
    };
    int* cnt = (int*)alloc((size_t)n * 4);
    int* rowptr = (int*)alloc((size_t)(n + 1) * 4);
    int* bsum = (int*)alloc((size_t)nb * 4);
    float* dinv = (float*)alloc((size_t)n * 4);
    unsigned int* csr = (unsigned int*)alloc((size_t)E * 4);
    int* cnt2 = (int*)alloc((size_t)n2 * 4);
    int* off2 = (int*)alloc((size_t)n2 * 4);
    int* bsum2 = (int*)alloc((size_t)nb2 * 4);
    int* tot2 = (int*)alloc(4);
    unsigned int* stage = (unsigned int*)alloc((size_t)E * 4);
    unsigned short* Bp1 = (unsigned short*)alloc((size_t)N1PACK * 2);
    unsigned short* Bp2 = (unsigned short*)alloc((size_t)N2PACK * 2);
    unsigned short* Hb = (unsigned short*)alloc((size_t)n * L1W * 2);
    unsigned char* Y8 = (unsigned char*)alloc((size_t)n * 256);
    unsigned char* T8 = (unsigned char*)alloc((size_t)n * 128);
    unsigned short* Ub = (unsigned short*)alloc((size_t)n * L2WP * 2);
    unsigned char* U8 = (unsigned char*)alloc((size_t)n * 128);
    unsigned short* T2a = (unsigned short*)alloc((size_t)n * C_OUT * 2);
    unsigned char* T8b = (unsigned char*)alloc((size_t)n * C_OUT);
    (void)ws_size;

    // 1. fused: per-node degree + bucket hist + weight pack (one pass)
    hipMemsetAsync(cnt, 0, (size_t)n * 4, stream);
    fhist_k<<<NBLK1 + PACKB, 256, 0, stream>>>(ei, W1_0, W1_1, W1_2, W2_0, W2_1, W2_2,
                                               cnt, cnt2, Bp1, Bp2, E);

    // 2. fused scans (node chain: rowptr+dinv; bucket chain: off2)
    fscan1_k<<<nb + nb2, 256, 0, stream>>>(cnt, bsum, n, cnt2, bsum2, n2, nb);
    fscan2_k<<<2, 256, 0, stream>>>(bsum, rowptr + n, nb, bsum2, tot2, nb2);
    fscan3_k<<<nb + nb2, 256, 0, stream>>>(cnt, bsum, rowptr, dinv, n,
                                           cnt2, bsum2, off2, n2, nb);

    // 3. binned stage, then FUSED scatter2 + layer-1 GEMM (scatter rides along)
    stage_k<<<NBLK1, 256, 0, stream>>>(ei, off2, stage, E);
    scmg1_k<<<NBUK + (n + 63) / 64, 256, 0, stream>>>(stage, off2, rowptr, dinv, csr, E,
                                                      x, Bp1, b1, Hb, Y8, n);

    // 4. layer-1 props
    prop256f_k<<<(n + 3) / 4, 256, 0, stream>>>(Y8, Hb, T8, rowptr, csr, dinv, b1, n);
    prop128f_k<<<(n + 3) / 4, 256, 0, stream>>>(T8, Hb, rowptr, csr, dinv, b1, n);

    // 5. layer 2 GEMM -> Ub bf16 (cols<48) + U8 fp8 (1 line/row)
    mgemm2_k<<<(n + 63) / 64, 256, 0, stream>>>(Hb, Bp2, Ub, U8, n);
    propU8_k<<<(n + 3) / 4, 256, 0, stream>>>(U8, T2a, T8b, rowptr, csr, dinv, n);

    // 6. fused second hop + log_softmax
    lsm_prop_k<<<(n + 3) / 4, 256, 0, stream>>>(Ub, T2a, T8b, rowptr, csr, dinv, b2, out, n);
}